// Round 11
// baseline (88.244 us; speedup 1.0000x reference)
//
#include <hip/hip_runtime.h>

#define HOP 512
#define MAX_NHAR 128
#define N_MAX 4410
#define SEGS16 16
#define CH16_MAX 112            // pad8(ceil(1764/16)); w<=1764 for f0>=100
#define PI_D 3.14159265358979323846

// ---------------------------------------------------------------------------
// Frame-parameter computation (bit-exact vs reference; absmax 0.0 since R1).
// ---------------------------------------------------------------------------
__device__ __forceinline__ void frame_params(double f0v, int& w, int& nhar, double& theta) {
    double f0d = f0v < 40.0 ? 40.0 : f0v;
    const double inv = 44100.0 / f0d;
    nhar = (int)fmin(floor(inv * 0.5), 128.0);
    w = 2 * (int)rint(inv * 2.0);
    if (w > N_MAX) w = N_MAX;
    theta = (2.0 * PI_D * f0d) / 44100.0;
}

__device__ __forceinline__ int chunk16_of(int w) {
    return (((w + SEGS16 - 1) / SEGS16) + 7) & ~7;   // per-seg span, x8
}

// ---------------------------------------------------------------------------
// Kernel A: cos table C[f][k] = cos(theta_f (k+1)). (R3-verified)
// ---------------------------------------------------------------------------
__global__ __launch_bounds__(128) void prep_kernel(
    const float* __restrict__ f0, double* __restrict__ ccos, int F)
{
    const int f = blockIdx.x, k = threadIdx.x;
    int w, nhar; double theta;
    frame_params((double)f0[f], w, nhar, theta);
    ccos[f * MAX_NHAR + k] = cos(theta * (double)(k + 1));
}

// ---------------------------------------------------------------------------
// Kernel B (hot): per-(frame, 2 segments) staged dual-stream real Goertzel.
// WHY THIS SHAPE (R10 post-mortem): 1024 frame-blocks are all co-resident ->
// static tail = worst CU ~1.67x mean, matching the measured 31 vs ~18us model.
// 8192 x 128-thread blocks -> 16 resident/CU (full 32 waves) + 4096 QUEUED:
// the HW scheduler backfills finished slots, bounding the tail at ~1 block.
// (R9's stealing failed by cutting bulk residency to 3/4; this keeps it full.
//  R3/R5's 64-thr blocks halved residency via the ~16 workgroup/CU cap.)
// Each wave owns one segment: stages its own chunk into a private LDS slice
// (no barriers anywhere: same-wave LDS deps are lgkmcnt-tracked, verified
// R5/R6), then runs the verified dual-stream Goertzel (k=lane, k+64; each
// sample read once per wave) and writes raw (s1,s2) partials.
// fp64 throughout: atan2 branch cut at +/-pi makes fp32 drift a 2*pi fail.
// ---------------------------------------------------------------------------
__global__ __launch_bounds__(128, 8) void goertzel16_kernel(
    const float* __restrict__ x, const float* __restrict__ f0,
    const double* __restrict__ ccos, double2* __restrict__ parts,
    int t, int F)
{
    __shared__ double sm[2][CH16_MAX];   // 1.75 KB: LDS never limits residency
    const int wave = threadIdx.x >> 6;   // 0..1
    const int lane = threadIdx.x & 63;
    const int frame = blockIdx.x >> 3;
    const int seg   = ((blockIdx.x & 7) << 1) | wave;   // 0..15

    int w, nhar; double theta;
    frame_params((double)f0[frame], w, nhar, theta);
    const int chunk = chunk16_of(w);     // 32..112
    const int j0 = seg * chunk;
    int lenp = 0;
    if (j0 < w) {
        const int l = w - j0;
        lenp = (l > chunk) ? chunk : ((l + 7) & ~7);    // padded length (x8)
    }

    // ---- stage this wave's Blackman-windowed chunk (verified math) ----
    double* smw = sm[wave];
    {
        const double c2pi_invw = (2.0 * PI_D) / (double)w;
        const int base = frame * HOP - (w >> 1) + j0;   // pad offset cancels
        for (int j = lane; j < lenp; j += 64) {         // <=2 iterations
            double outv = 0.0;
            if (j0 + j < w) {
                const int ix = base + j;
                const double val = (ix >= 0 && ix < t) ? (double)x[ix] : 0.0;
                const double c1 = cos(c2pi_invw * (double)(j0 + j));
                // 0.42 - 0.5 c + 0.08 (2c^2-1) = 0.34 - 0.5 c + 0.16 c^2
                const double win = fma(0.16, c1 * c1, 0.34) - 0.5 * c1;
                outv = val * win;
            }
            smw[j] = outv;
        }
    }
    // no barrier: producer wave == consumer wave (verified R5/R6)

    // ---- dual-stream Goertzel: harmonics k=lane, k=lane+64 ----
    const double Ca = 2.0 * ccos[frame * MAX_NHAR + lane];
    const double Cb = 2.0 * ccos[frame * MAX_NHAR + lane + 64];
    double s1a = 0.0, s2a = 0.0, s1b = 0.0, s2b = 0.0;
    const double2* __restrict__ sm2 = (const double2*)smw;   // 16B-aligned slice

    if (nhar > 64) {
        for (int jb = 0; jb < lenp; jb += 8) {
            const int h = jb >> 1;
            const double2 v0 = sm2[h], v1 = sm2[h + 1], v2 = sm2[h + 2], v3 = sm2[h + 3];
            const double xv[8] = {v0.x, v0.y, v1.x, v1.y, v2.x, v2.y, v3.x, v3.y};
            #pragma unroll
            for (int u = 0; u < 8; ++u) {
                const double na = fma(Ca, s1a, xv[u] - s2a);
                const double nb = fma(Cb, s1b, xv[u] - s2b);
                s2a = s1a; s1a = na;
                s2b = s1b; s1b = nb;
            }
        }
    } else {
        // harmonics 65..128 all masked for this frame: single stream
        for (int jb = 0; jb < lenp; jb += 8) {
            const int h = jb >> 1;
            const double2 v0 = sm2[h], v1 = sm2[h + 1], v2 = sm2[h + 2], v3 = sm2[h + 3];
            const double xv[8] = {v0.x, v0.y, v1.x, v1.y, v2.x, v2.y, v3.x, v3.y};
            #pragma unroll
            for (int u = 0; u < 8; ++u) {
                const double na = fma(Ca, s1a, xv[u] - s2a);
                s2a = s1a; s1a = na;
            }
        }
    }
    // unconditional writes: parts is 0xAA-poisoned, every (seg,k) slot covered
    double2* p = parts + (size_t)(frame * SEGS16 + seg) * MAX_NHAR;
    p[lane]      = make_double2(s1a, s2a);
    p[lane + 64] = make_double2(s1b, s2b);
}

// ---------------------------------------------------------------------------
// Kernel C: combine 16 partials with the R4-R10-verified (SEGS-parametric)
// rotation algebra, scale, amp/phase, transpose-write.
// partial_y(seg) = P (s1 - e^{-iw} s2), P = e^{-iw (j0 + steps - 1)};
// full segs: steps == chunk -> P advances by Q = e^{-iw chunk} (recurrence);
// last data seg uses padded end (endlast); segs past slast are (0,0) -> 0.
// ---------------------------------------------------------------------------
__global__ __launch_bounds__(128) void finalize16_kernel(
    const float* __restrict__ f0, const double2* __restrict__ parts,
    float* __restrict__ out, int F)
{
    const int frame = blockIdx.x;
    const int tid = threadIdx.x;

    int w, nhar; double theta;
    frame_params((double)f0[frame], w, nhar, theta);
    const int chunk = chunk16_of(w);
    const int slast = (w - 1) / chunk;
    const int endlast = slast * chunk + (((w - slast * chunk) + 7) & ~7);
    const double omega = theta * (double)(tid + 1);

    double sw, cw; sincos(omega, &sw, &cw);                      // e^{-iw}=(cw,-sw)
    double sq, cq; sincos(omega * (double)chunk, &sq, &cq);      // Q=(cq,-sq)
    double sl, cl; sincos(omega * (double)(endlast - 1), &sl, &cl);

    double Rr = cq * cw + sq * sw, Ri = cq * sw - sq * cw;       // e^{-iw(chunk-1)}
    double yr = 0.0, yi = 0.0;
    const double2* p = parts + (size_t)frame * SEGS16 * MAX_NHAR + tid;
    #pragma unroll
    for (int s = 0; s < SEGS16; ++s) {
        const double2 v = p[(size_t)s * MAX_NHAR];
        const double tr = fma(-cw, v.y, v.x);                    // s1 - cw*s2
        const double ti = sw * v.y;                              // + i sw*s2
        const double Pr = (s == slast) ? cl : Rr;
        const double Pi = (s == slast) ? -sl : Ri;
        yr = fma(Pr, tr, fma(-Pi, ti, yr));
        yi = fma(Pr, ti, fma( Pi, tr, yi));
        const double nr = Rr * cq + Ri * sq;                     // R *= Q
        Ri = Ri * cq - Rr * sq; Rr = nr;
    }
    const double scale = 2.381 / (double)((w >> 1) + 1);
    yr *= scale; yi *= scale;

    float ampl = 0.0f, ph = 0.0f;
    if (tid < nhar) {
        ampl = (float)sqrt(yr * yr + yi * yi);
        ph   = (float)atan2(yi, yr);
    }
    out[tid * F + frame] = ampl;                 // ampl  (MAX_NHAR, F)
    out[MAX_NHAR * F + tid * F + frame] = ph;    // phase (MAX_NHAR, F)
}

// ---------------------------------------------------------------------------
// Fallback: single-kernel direct DFT (R1, verified) if ws is too small.
// ---------------------------------------------------------------------------
__global__ __launch_bounds__(128) void czt_direct_kernel(
    const float* __restrict__ x, const float* __restrict__ f0,
    float* __restrict__ out, int t, int F)
{
    __shared__ double sm[N_MAX];
    const int frame = blockIdx.x;
    const int tid = threadIdx.x;
    int w, nhar; double theta;
    frame_params((double)f0[frame], w, nhar, theta);
    {
        const double invw = 1.0 / (double)w;
        double sa, ca, ss, cs;
        sincos((2.0 * PI_D) * ((double)tid * invw), &sa, &ca);
        sincos((2.0 * PI_D) * (128.0 * invw), &ss, &cs);
        double zr = ca, zi = sa;
        const int base = frame * HOP - (w >> 1);
        for (int j = tid; j < w; j += 128) {
            const int ix = base + j;
            const double val = (ix >= 0 && ix < t) ? (double)x[ix] : 0.0;
            const double c = zr;
            const double win = 0.42 - 0.5 * c + 0.08 * (2.0 * c * c - 1.0);
            sm[j] = val * win;
            const double nzr = zr * cs - zi * ss;
            zi = zr * ss + zi * cs;
            zr = nzr;
        }
    }
    __syncthreads();
    double s, c;
    sincos(theta * (double)(tid + 1), &s, &c);
    const double rr = c, ri = -s;
    const double r2r = rr * rr - ri * ri, r2i = 2.0 * rr * ri;
    const double r4r = r2r * r2r - r2i * r2i, r4i = 2.0 * r2r * r2i;
    const double r3r = r2r * rr - r2i * ri, r3i = r2r * ri + r2i * rr;
    double z0r = 1.0, z0i = 0.0, z1r = rr, z1i = ri;
    double z2r = r2r, z2i = r2i, z3r = r3r, z3i = r3i;
    double a0r = 0, a0i = 0, a1r = 0, a1i = 0, a2r = 0, a2i = 0, a3r = 0, a3i = 0;
    const int w4 = w & ~3;
    for (int j = 0; j < w4; j += 4) {
        const double s0 = sm[j], s1 = sm[j + 1], s2 = sm[j + 2], s3 = sm[j + 3];
        double tr;
        a0r = fma(s0, z0r, a0r); a0i = fma(s0, z0i, a0i);
        tr = z0r * r4r - z0i * r4i; z0i = z0r * r4i + z0i * r4r; z0r = tr;
        a1r = fma(s1, z1r, a1r); a1i = fma(s1, z1i, a1i);
        tr = z1r * r4r - z1i * r4i; z1i = z1r * r4i + z1i * r4r; z1r = tr;
        a2r = fma(s2, z2r, a2r); a2i = fma(s2, z2i, a2i);
        tr = z2r * r4r - z2i * r4i; z2i = z2r * r4i + z2i * r4r; z2r = tr;
        a3r = fma(s3, z3r, a3r); a3i = fma(s3, z3i, a3i);
        tr = z3r * r4r - z3i * r4i; z3i = z3r * r4i + z3i * r4r; z3r = tr;
    }
    if (w4 < w) {
        const double s0 = sm[w4], s1 = sm[w4 + 1];
        a0r = fma(s0, z0r, a0r); a0i = fma(s0, z0i, a0i);
        a1r = fma(s1, z1r, a1r); a1i = fma(s1, z1i, a1i);
    }
    double yr = (a0r + a1r) + (a2r + a3r);
    double yi = (a0i + a1i) + (a2i + a3i);
    const double scale = 2.381 / (double)((w >> 1) + 1);
    yr *= scale; yi *= scale;
    float ampl = 0.0f, ph = 0.0f;
    if (tid < nhar) {
        ampl = (float)sqrt(yr * yr + yi * yi);
        ph   = (float)atan2(yi, yr);
    }
    out[tid * F + frame] = ampl;
    out[MAX_NHAR * F + tid * F + frame] = ph;
}

extern "C" void kernel_launch(void* const* d_in, const int* in_sizes, int n_in,
                              void* d_out, int out_size, void* d_ws, size_t ws_size,
                              hipStream_t stream) {
    const float* x  = (const float*)d_in[0];
    const float* f0 = (const float*)d_in[1];
    float* out = (float*)d_out;
    const int t = in_sizes[0];   // samples
    const int F = in_sizes[1];   // frames

    const size_t ccos_b  = (size_t)F * MAX_NHAR * sizeof(double);            // 1 MB
    const size_t parts_b = (size_t)F * SEGS16 * MAX_NHAR * sizeof(double2);  // 33.5 MB
    if (ws_size >= ccos_b + parts_b) {
        double*  ccos  = (double*)d_ws;
        double2* parts = (double2*)((char*)d_ws + ccos_b);
        prep_kernel<<<F, 128, 0, stream>>>(f0, ccos, F);
        goertzel16_kernel<<<F * 8, 128, 0, stream>>>(x, f0, ccos, parts, t, F);
        finalize16_kernel<<<F, 128, 0, stream>>>(f0, parts, out, F);
    } else {
        czt_direct_kernel<<<F, 128, 0, stream>>>(x, f0, out, t, F);
    }
}

// Round 12
// 78.598 us; speedup vs baseline: 1.1227x; 1.1227x over previous
//
#include <hip/hip_runtime.h>

#define HOP 512
#define MAX_NHAR 128
#define N_MAX 4410
#define SEGS 10
#define NTHR 640                // 10 waves: 3 blocks/CU (30/32 waves) + 256-block queue
#define SM_N 4424               // N_MAX + pad slots (covers padded last-seg reads)
#define PI_D 3.14159265358979323846

// ---------------------------------------------------------------------------
// Frame-parameter computation (bit-exact vs reference; absmax 0.0 since R1).
// ---------------------------------------------------------------------------
__device__ __forceinline__ void frame_params(double f0v, int& w, int& nhar, double& theta) {
    double f0d = f0v < 40.0 ? 40.0 : f0v;
    const double inv = 44100.0 / f0d;
    nhar = (int)fmin(floor(inv * 0.5), 128.0);
    w = 2 * (int)rint(inv * 2.0);
    if (w > N_MAX) w = N_MAX;
    theta = (2.0 * PI_D * f0d) / 44100.0;
}

// ---------------------------------------------------------------------------
// Fully fused kernel: one block per frame, 640 threads = 10 waves, SEGS=10.
// R10 body (75.3us, absmax 0.0) with one structural change: 10-wave blocks
// cap residency at 3 blocks/CU (30/32 wave slots, 94%) so 256 of the 1024
// blocks QUEUE -- the HW backfills CUs that drew light frames, attacking the
// ~1.67x static-tail factor that R10's exactly-resident grid could not
// (R8/R9 stealing and R11 multi-kernel both regressed by breaking fusion or
// bulk residency; this keeps the verified one-launch structure intact).
// Combine algebra is SEGS-parametric: R11 ran SEGS=16 w/ empty trailing segs
// at absmax 0.0, so SEGS=10 (slast<9 when w<~720, else 9) is covered.
//   phase 1: coalesced staging of Blackman-windowed frame into LDS + cos table
//   phase 2: wave s = dual-stream real Goertzel on segment s (k=lane, k+64)
//   phase 3: partials through LDS (aliased over staging buffer, 20KB < 35KB)
//   phase 4: threads 0..127 combine with padded-segment rotation algebra
// fp64 throughout: atan2 branch cut at +/-pi makes fp32 drift a 2*pi fail.
// ---------------------------------------------------------------------------
__global__ __launch_bounds__(NTHR, 8) void czt_fused_kernel(
    const float* __restrict__ x, const float* __restrict__ f0,
    float* __restrict__ out, int t, int F)
{
    __shared__ double sm[SM_N];          // staged frame; start reused for partials
    __shared__ double cc[MAX_NHAR];      // cos(theta*(k+1))
    const int tid  = threadIdx.x;        // 0..639
    const int wave = tid >> 6;           // 0..9 == segment id
    const int lane = tid & 63;

    const int frame = blockIdx.x;
    int w, nhar; double theta;
    frame_params((double)f0[frame], w, nhar, theta);
    const int chunk = (((w + SEGS - 1) / SEGS) + 7) & ~7;   // per-seg span, x8

    // ---- phase 1: stage windowed frame (coalesced), zero pad, cos table ----
    {
        const double c2pi_invw = (2.0 * PI_D) / (double)w;
        const int base = frame * HOP - (w >> 1);             // pad offset cancels
        for (int j = tid; j < w; j += NTHR) {
            const int ix = base + j;
            const double val = (ix >= 0 && ix < t) ? (double)x[ix] : 0.0;
            const double c1 = cos(c2pi_invw * (double)j);
            // 0.42 - 0.5 c + 0.08 (2c^2-1) = 0.34 - 0.5 c + 0.16 c^2
            const double win = fma(0.16, c1 * c1, 0.34) - 0.5 * c1;
            sm[j] = val * win;
        }
        if (tid < 8) sm[w + tid] = 0.0;                      // padded last-seg reads
        if (tid < MAX_NHAR) cc[tid] = cos(theta * (double)(tid + 1));
    }
    __syncthreads();

    // ---- phase 2: dual-stream Goertzel on this wave's segment ----
    const int j0 = wave * chunk;
    int lenp = 0;
    if (j0 < w) {
        const int l = w - j0;
        lenp = (l > chunk) ? chunk : ((l + 7) & ~7);         // padded length (x8)
    }
    const double Ca = 2.0 * cc[lane];
    const double Cb = 2.0 * cc[lane + 64];
    double s1a = 0.0, s2a = 0.0, s1b = 0.0, s2b = 0.0;
    const double2* __restrict__ sm2 = (const double2*)(sm + j0);  // j0 x8 -> 16B aligned

    if (nhar > 64) {
        for (int jb = 0; jb < lenp; jb += 8) {
            const int h = jb >> 1;
            const double2 v0 = sm2[h], v1 = sm2[h + 1], v2 = sm2[h + 2], v3 = sm2[h + 3];
            const double xv[8] = {v0.x, v0.y, v1.x, v1.y, v2.x, v2.y, v3.x, v3.y};
            #pragma unroll
            for (int u = 0; u < 8; ++u) {
                const double na = fma(Ca, s1a, xv[u] - s2a);
                const double nb = fma(Cb, s1b, xv[u] - s2b);
                s2a = s1a; s1a = na;
                s2b = s1b; s1b = nb;
            }
        }
    } else {
        // harmonics 65..128 all masked for this frame: single stream
        for (int jb = 0; jb < lenp; jb += 8) {
            const int h = jb >> 1;
            const double2 v0 = sm2[h], v1 = sm2[h + 1], v2 = sm2[h + 2], v3 = sm2[h + 3];
            const double xv[8] = {v0.x, v0.y, v1.x, v1.y, v2.x, v2.y, v3.x, v3.y};
            #pragma unroll
            for (int u = 0; u < 8; ++u) {
                const double na = fma(Ca, s1a, xv[u] - s2a);
                s2a = s1a; s1a = na;
            }
        }
    }
    __syncthreads();                      // all waves done READING sm

    // ---- phase 3: partials through LDS (alias over staging buffer) ----
    double2* parts = (double2*)sm;        // [seg][k] double2: 10*128*16B = 20 KB
    parts[wave * MAX_NHAR + lane]      = make_double2(s1a, s2a);
    parts[wave * MAX_NHAR + lane + 64] = make_double2(s1b, s2b);  // zeros if 1-stream
    __syncthreads();

    // ---- phase 4: combine (verified SEGS-parametric algebra), amp/phase ----
    if (tid < MAX_NHAR) {
        const int slast = (w - 1) / chunk;
        const int endlast = slast * chunk + (((w - slast * chunk) + 7) & ~7);
        const double omega = theta * (double)(tid + 1);

        double sw, cw; sincos(omega, &sw, &cw);                  // e^{-iw} = (cw,-sw)
        double sq, cq; sincos(omega * (double)chunk, &sq, &cq);  // Q = (cq,-sq)
        double sl, cl; sincos(omega * (double)(endlast - 1), &sl, &cl);

        double Rr = cq * cw + sq * sw, Ri = cq * sw - sq * cw;   // e^{-iw(chunk-1)}
        double yr = 0.0, yi = 0.0;
        #pragma unroll
        for (int s = 0; s < SEGS; ++s) {
            const double2 v = parts[s * MAX_NHAR + tid];
            const double tr = fma(-cw, v.y, v.x);                // s1 - cw*s2
            const double ti = sw * v.y;                          // + i sw*s2
            const double Pr = (s == slast) ? cl : Rr;
            const double Pi = (s == slast) ? -sl : Ri;
            yr = fma(Pr, tr, fma(-Pi, ti, yr));
            yi = fma(Pr, ti, fma( Pi, tr, yi));
            const double nr = Rr * cq + Ri * sq;                 // R *= Q
            Ri = Ri * cq - Rr * sq; Rr = nr;
        }
        const double scale = 2.381 / (double)((w >> 1) + 1);
        yr *= scale; yi *= scale;

        float ampl = 0.0f, ph = 0.0f;
        if (tid < nhar) {
            ampl = (float)sqrt(yr * yr + yi * yi);
            ph   = (float)atan2(yi, yr);
        }
        out[tid * F + frame] = ampl;                 // ampl  (MAX_NHAR, F)
        out[MAX_NHAR * F + tid * F + frame] = ph;    // phase (MAX_NHAR, F)
    }
}

extern "C" void kernel_launch(void* const* d_in, const int* in_sizes, int n_in,
                              void* d_out, int out_size, void* d_ws, size_t ws_size,
                              hipStream_t stream) {
    const float* x  = (const float*)d_in[0];
    const float* f0 = (const float*)d_in[1];
    float* out = (float*)d_out;
    const int t = in_sizes[0];   // samples
    const int F = in_sizes[1];   // frames
    czt_fused_kernel<<<F, NTHR, 0, stream>>>(x, f0, out, t, F);
}

// Round 13
// 74.910 us; speedup vs baseline: 1.1780x; 1.0492x over previous
//
#include <hip/hip_runtime.h>

#define HOP 512
#define MAX_NHAR 128
#define N_MAX 4410
#define SEGS 8
#define SM_N 4424               // N_MAX + 8 zero-pad slots (covers padded last-seg reads)
#define PI_D 3.14159265358979323846

// ---------------------------------------------------------------------------
// TERMINAL KERNEL == R10 exactly (best measured: 75.3us, absmax 0.0).
// Session findings baked into this shape:
//  - Direct harmonic DFT via dual-stream real Goertzel (2 fp64 ops/sample/
//    stream) replaces the reference's Bluestein FFT (~50x less work).
//  - Full fusion (stage+Goertzel+combine in one launch) beats every split:
//    multi-kernel variants re-pay launch gaps + parts HBM round-trips
//    (R2-R5, R11), and per-wave prologues dominate small kernels.
//  - Static 1024-block grid at full residency (512 thr, launch_bounds(512,8)
//    -> 64 VGPR -> 4 blocks/CU) beats all dynamic schemes: work-stealing
//    (R8/R9) and queued-backfill shapes (R11/R12) each regressed 3-16us.
//  - fp64 EVERYWHERE is mandatory: outputs pass through atan2 on
//    Rayleigh(0.05)-distributed |y|; E[2pi branch flips] ~ 131K*E[eps/|y|]/pi
//    means the absolute error budget is ~1e-8 -- fp32 window/coeffs (1e-7+)
//    have ~O(1) expected flips. fp64 keeps absmax at exactly 0.0.
// Phases: (1) coalesced fp64 Blackman staging into LDS + cos table;
// (2) wave s = dual-stream Goertzel on segment s (k=lane, k+64; each sample
// broadcast-read once); (3) partials via LDS (aliased); (4) tid<128 combines
// with the SEGS-parametric padded-segment rotation algebra, scale, amp/phase.
// ---------------------------------------------------------------------------
__device__ __forceinline__ void frame_params(double f0v, int& w, int& nhar, double& theta) {
    double f0d = f0v < 40.0 ? 40.0 : f0v;
    const double inv = 44100.0 / f0d;
    nhar = (int)fmin(floor(inv * 0.5), 128.0);
    w = 2 * (int)rint(inv * 2.0);
    if (w > N_MAX) w = N_MAX;
    theta = (2.0 * PI_D * f0d) / 44100.0;
}

__global__ __launch_bounds__(512, 8) void czt_fused_kernel(
    const float* __restrict__ x, const float* __restrict__ f0,
    float* __restrict__ out, int t, int F)
{
    __shared__ double sm[SM_N];          // staged frame; first 16 KB reused for partials
    __shared__ double cc[MAX_NHAR];      // cos(theta*(k+1))
    const int tid  = threadIdx.x;        // 0..511
    const int wave = tid >> 6;           // 0..7 == segment id
    const int lane = tid & 63;

    const int frame = blockIdx.x;
    int w, nhar; double theta;
    frame_params((double)f0[frame], w, nhar, theta);
    const int chunk = (((w + SEGS - 1) / SEGS) + 7) & ~7;   // per-seg span, x8

    // ---- phase 1: stage windowed frame (coalesced), zero pad, cos table ----
    {
        const double c2pi_invw = (2.0 * PI_D) / (double)w;
        const int base = frame * HOP - (w >> 1);             // pad offset cancels
        for (int j = tid; j < w; j += 512) {
            const int ix = base + j;
            const double val = (ix >= 0 && ix < t) ? (double)x[ix] : 0.0;
            const double c1 = cos(c2pi_invw * (double)j);
            // 0.42 - 0.5 c + 0.08 (2c^2-1) = 0.34 - 0.5 c + 0.16 c^2
            const double win = fma(0.16, c1 * c1, 0.34) - 0.5 * c1;
            sm[j] = val * win;
        }
        if (tid < 8) sm[w + tid] = 0.0;                      // padded last-seg reads
        if (tid < MAX_NHAR) cc[tid] = cos(theta * (double)(tid + 1));
    }
    __syncthreads();

    // ---- phase 2: dual-stream Goertzel on this wave's segment ----
    const int j0 = wave * chunk;
    int lenp = 0;
    if (j0 < w) {
        const int l = w - j0;
        lenp = (l > chunk) ? chunk : ((l + 7) & ~7);         // padded length (x8)
    }
    const double Ca = 2.0 * cc[lane];
    const double Cb = 2.0 * cc[lane + 64];
    double s1a = 0.0, s2a = 0.0, s1b = 0.0, s2b = 0.0;
    const double2* __restrict__ sm2 = (const double2*)(sm + j0);  // j0 x8 -> 16B aligned

    if (nhar > 64) {
        for (int jb = 0; jb < lenp; jb += 8) {
            const int h = jb >> 1;
            const double2 v0 = sm2[h], v1 = sm2[h + 1], v2 = sm2[h + 2], v3 = sm2[h + 3];
            const double xv[8] = {v0.x, v0.y, v1.x, v1.y, v2.x, v2.y, v3.x, v3.y};
            #pragma unroll
            for (int u = 0; u < 8; ++u) {
                const double na = fma(Ca, s1a, xv[u] - s2a);
                const double nb = fma(Cb, s1b, xv[u] - s2b);
                s2a = s1a; s1a = na;
                s2b = s1b; s1b = nb;
            }
        }
    } else {
        // harmonics 65..128 all masked for this frame: single stream
        for (int jb = 0; jb < lenp; jb += 8) {
            const int h = jb >> 1;
            const double2 v0 = sm2[h], v1 = sm2[h + 1], v2 = sm2[h + 2], v3 = sm2[h + 3];
            const double xv[8] = {v0.x, v0.y, v1.x, v1.y, v2.x, v2.y, v3.x, v3.y};
            #pragma unroll
            for (int u = 0; u < 8; ++u) {
                const double na = fma(Ca, s1a, xv[u] - s2a);
                s2a = s1a; s1a = na;
            }
        }
    }
    __syncthreads();                      // all waves done READING sm

    // ---- phase 3: partials through LDS (alias over staging buffer) ----
    double2* parts = (double2*)sm;        // [seg][k] double2: 8*128*16B = 16 KB
    parts[wave * MAX_NHAR + lane]      = make_double2(s1a, s2a);
    parts[wave * MAX_NHAR + lane + 64] = make_double2(s1b, s2b);  // zeros if 1-stream
    __syncthreads();

    // ---- phase 4: combine (verified rotation algebra), amp/phase ----
    if (tid < MAX_NHAR) {
        const int slast = (w - 1) / chunk;
        const int endlast = slast * chunk + (((w - slast * chunk) + 7) & ~7);
        const double omega = theta * (double)(tid + 1);

        double sw, cw; sincos(omega, &sw, &cw);                  // e^{-iw} = (cw,-sw)
        double sq, cq; sincos(omega * (double)chunk, &sq, &cq);  // Q = (cq,-sq)
        double sl, cl; sincos(omega * (double)(endlast - 1), &sl, &cl);

        double Rr = cq * cw + sq * sw, Ri = cq * sw - sq * cw;   // e^{-iw(chunk-1)}
        double yr = 0.0, yi = 0.0;
        #pragma unroll
        for (int s = 0; s < SEGS; ++s) {
            const double2 v = parts[s * MAX_NHAR + tid];
            const double tr = fma(-cw, v.y, v.x);                // s1 - cw*s2
            const double ti = sw * v.y;                          // + i sw*s2
            const double Pr = (s == slast) ? cl : Rr;
            const double Pi = (s == slast) ? -sl : Ri;
            yr = fma(Pr, tr, fma(-Pi, ti, yr));
            yi = fma(Pr, ti, fma( Pi, tr, yi));
            const double nr = Rr * cq + Ri * sq;                 // R *= Q
            Ri = Ri * cq - Rr * sq; Rr = nr;
        }
        const double scale = 2.381 / (double)((w >> 1) + 1);
        yr *= scale; yi *= scale;

        float ampl = 0.0f, ph = 0.0f;
        if (tid < nhar) {
            ampl = (float)sqrt(yr * yr + yi * yi);
            ph   = (float)atan2(yi, yr);
        }
        out[tid * F + frame] = ampl;                 // ampl  (MAX_NHAR, F)
        out[MAX_NHAR * F + tid * F + frame] = ph;    // phase (MAX_NHAR, F)
    }
}

extern "C" void kernel_launch(void* const* d_in, const int* in_sizes, int n_in,
                              void* d_out, int out_size, void* d_ws, size_t ws_size,
                              hipStream_t stream) {
    const float* x  = (const float*)d_in[0];
    const float* f0 = (const float*)d_in[1];
    float* out = (float*)d_out;
    const int t = in_sizes[0];   // samples
    const int F = in_sizes[1];   // frames
    czt_fused_kernel<<<F, 512, 0, stream>>>(x, f0, out, t, F);
}